// Round 2
// baseline (101.613 us; speedup 1.0000x reference)
//
#include <hip/hip_runtime.h>

typedef __attribute__((ext_vector_type(8))) short s16x8;
typedef __attribute__((ext_vector_type(4))) short s16x4;
typedef __attribute__((ext_vector_type(4))) float fx4;

#define DEVINL __device__ __forceinline__

constexpr int EMBED = 768;
constexpr int HD    = 64;
constexpr int NB    = 16;
constexpr int LEN   = 1024;
constexpr int M_TOT = NB * LEN; // 16384
constexpr int WELEM = HD * EMBED; // 49152

// fp32 -> bf16 (RNE). Inputs here are well-behaved (no NaN/Inf).
DEVINL short f2bf(float f) {
  union { float f; unsigned u; } c; c.f = f;
  unsigned r = c.u + 0x7FFFu + ((c.u >> 16) & 1u);
  return (short)(r >> 16);
}

DEVINL fx4 mfma16(s16x8 a, s16x8 b, fx4 c) {
  return __builtin_amdgcn_mfma_f32_16x16x32_bf16(a, b, c, 0, 0, 0);
}

// ---------------------------------------------------------------------------
// One-shot: convert Wq|Wk|Wv (each 64x768 fp32) to bf16, packed [3][49152].
// ---------------------------------------------------------------------------
__global__ __launch_bounds__(256) void convert_w_kernel(
    const float* __restrict__ a, const float* __restrict__ b,
    const float* __restrict__ c, short* __restrict__ out)
{
  const int g   = blockIdx.x * 256 + threadIdx.x;   // 18432 threads, 8 elem each
  const int seg = g / (WELEM / 8);
  const int off = (g % (WELEM / 8)) * 8;
  const float* src = (seg == 0) ? a : (seg == 1) ? b : c;
  fx4 v0 = *reinterpret_cast<const fx4*>(src + off);
  fx4 v1 = *reinterpret_cast<const fx4*>(src + off + 4);
  s16x8 o;
#pragma unroll
  for (int j = 0; j < 4; ++j) { o[j] = f2bf(v0[j]); o[j + 4] = f2bf(v1[j]); }
  *reinterpret_cast<s16x8*>(out + (size_t)seg * WELEM + off) = o;
}

// ---------------------------------------------------------------------------
// Projection (LDS-free): Y[m][d] = bf16( X[m][:] @ W[d][:] + b[d] )
// Swapped MFMA: A = W-tile (d rows), B = X-tile (m cols) -> D col = m = fr,
// row = d = c*16+fg*4+r -> vectorized 8B stores.
// 4 independent waves/block, 16 rows each, no barriers; unroll keeps many
// HBM loads in flight (1 wave/SIMD -> ILP is the only latency hiding).
// ---------------------------------------------------------------------------
__global__ __launch_bounds__(256, 1) void proj_q_kernel(
    const float* __restrict__ X, const short* __restrict__ Wb,
    const float* __restrict__ bias, short* __restrict__ Y)
{
  const int t = threadIdx.x, lane = t & 63, wv = t >> 6;
  const int fr = lane & 15, fg = lane >> 4;
  const int row0 = blockIdx.x * 64 + wv * 16;

  fx4 acc[4];
#pragma unroll
  for (int c = 0; c < 4; ++c) acc[c] = fx4{0.f, 0.f, 0.f, 0.f};

  const float* xp = X + (size_t)(row0 + fr) * EMBED + fg * 8;
#pragma unroll 8
  for (int k0 = 0; k0 < EMBED; k0 += 32) {
    fx4 x0 = *reinterpret_cast<const fx4*>(xp + k0);
    fx4 x1 = *reinterpret_cast<const fx4*>(xp + k0 + 4);
    s16x8 xa;
#pragma unroll
    for (int j = 0; j < 4; ++j) { xa[j] = f2bf(x0[j]); xa[j + 4] = f2bf(x1[j]); }
#pragma unroll
    for (int c = 0; c < 4; ++c) {
      s16x8 wf = *reinterpret_cast<const s16x8*>(
          Wb + (size_t)(c * 16 + fr) * EMBED + k0 + fg * 8);
      acc[c] = mfma16(wf, xa, acc[c]);
    }
  }
#pragma unroll
  for (int c = 0; c < 4; ++c) {
    fx4 bv = *reinterpret_cast<const fx4*>(bias + c * 16 + fg * 4);
    s16x4 o;
#pragma unroll
    for (int r = 0; r < 4; ++r) o[r] = f2bf(acc[c][r] + bv[r]);
    *reinterpret_cast<s16x4*>(Y + (size_t)(row0 + fr) * HD + c * 16 + fg * 4) = o;
  }
}

// enc -> K [b,kv,64] bf16 and V^T [b,64,kv] bf16, LDS-free.
__global__ __launch_bounds__(256, 1) void proj_kv_kernel(
    const float* __restrict__ X,
    const short* __restrict__ Wkb, const float* __restrict__ bk,
    const short* __restrict__ Wvb, const float* __restrict__ bv,
    short* __restrict__ Kout, short* __restrict__ VT)
{
  const int t = threadIdx.x, lane = t & 63, wv = t >> 6;
  const int fr = lane & 15, fg = lane >> 4;
  const int row0 = blockIdx.x * 64 + wv * 16;

  fx4 kacc[4], vacc[4];
#pragma unroll
  for (int c = 0; c < 4; ++c) {
    kacc[c] = fx4{0.f, 0.f, 0.f, 0.f};
    vacc[c] = fx4{0.f, 0.f, 0.f, 0.f};
  }

  const float* xp = X + (size_t)(row0 + fr) * EMBED + fg * 8;
#pragma unroll 4
  for (int k0 = 0; k0 < EMBED; k0 += 32) {
    fx4 x0 = *reinterpret_cast<const fx4*>(xp + k0);
    fx4 x1 = *reinterpret_cast<const fx4*>(xp + k0 + 4);
    s16x8 xa;
#pragma unroll
    for (int j = 0; j < 4; ++j) { xa[j] = f2bf(x0[j]); xa[j + 4] = f2bf(x1[j]); }
#pragma unroll
    for (int c = 0; c < 4; ++c) {
      s16x8 wkf = *reinterpret_cast<const s16x8*>(
          Wkb + (size_t)(c * 16 + fr) * EMBED + k0 + fg * 8);
      s16x8 wvf = *reinterpret_cast<const s16x8*>(
          Wvb + (size_t)(c * 16 + fr) * EMBED + k0 + fg * 8);
      kacc[c] = mfma16(wkf, xa, kacc[c]);
      vacc[c] = mfma16(wvf, xa, vacc[c]);
    }
  }
  const int bidx  = row0 >> 10;            // 64 | 1024: no batch straddle
  const int kvpos = (row0 & 1023) + fr;
#pragma unroll
  for (int c = 0; c < 4; ++c) {
    fx4 bkv = *reinterpret_cast<const fx4*>(bk + c * 16 + fg * 4);
    fx4 bvv = *reinterpret_cast<const fx4*>(bv + c * 16 + fg * 4);
    s16x4 o;
#pragma unroll
    for (int r = 0; r < 4; ++r) {
      o[r] = f2bf(kacc[c][r] + bkv[r]);
      const int d = c * 16 + fg * 4 + r;
      VT[((size_t)bidx * HD + d) * LEN + kvpos] = f2bf(vacc[c][r] + bvv[r]);
    }
    *reinterpret_cast<s16x4*>(Kout + (size_t)(row0 + fr) * HD + c * 16 + fg * 4) = o;
  }
}

// ---------------------------------------------------------------------------
// Flash attention, swapped operands. 4 waves/block, 16 q rows/wave, KVBLK=64.
// S^T = mfma(K, Q): lane fr owns q-row fr -> per-lane softmax (4 shfl/iter).
// H^T = mfma(V^T, P): stats & rescale lane-local; output is a 16B vec store.
// K register double-buffer prefetch; V issued before QK^T; P via small LDS
// tile (vectorized b64 writes / b128 reads, wave-internal ordering only).
// ---------------------------------------------------------------------------
__global__ __launch_bounds__(256, 1) void attn_kernel(
    const short* __restrict__ Q, const short* __restrict__ K,
    const short* __restrict__ VT, float* __restrict__ Out)
{
  __shared__ short Plds[4][16][72];
  const int t = threadIdx.x, lane = t & 63, wv = t >> 6;
  const int fr = lane & 15, fg = lane >> 4;
  const int b  = blockIdx.x >> 4;
  const int qrow = (blockIdx.x & 15) * 64 + wv * 16;

  const short* Qb  = Q  + (size_t)b * LEN * HD;
  const short* Kb  = K  + (size_t)b * LEN * HD;
  const short* VTb = VT + (size_t)b * HD * LEN;

  s16x8 qa0 = *reinterpret_cast<const s16x8*>(Qb + (size_t)(qrow + fr) * HD + fg * 8);
  s16x8 qa1 = *reinterpret_cast<const s16x8*>(Qb + (size_t)(qrow + fr) * HD + 32 + fg * 8);

  fx4 hacc[4];
#pragma unroll
  for (int c = 0; c < 4; ++c) hacc[c] = fx4{0.f, 0.f, 0.f, 0.f};
  float mrun = -1e30f, lsum = 0.f;
  const float SC = 0.125f * 1.44269504088896340736f;  // 1/sqrt(64) * log2(e)

  s16x8 kA[4][2], kB[4][2];
#pragma unroll
  for (int s = 0; s < 4; ++s) {
    const short* kp = Kb + (size_t)(s * 16 + fr) * HD + fg * 8;
    kA[s][0] = *reinterpret_cast<const s16x8*>(kp);
    kA[s][1] = *reinterpret_cast<const s16x8*>(kp + 32);
  }

#pragma unroll
  for (int it = 0; it < LEN / 64; ++it) {
    const int kv0 = it * 64;
    // V for this tile: issue early, consumed after softmax.
    s16x8 vb[4][2];
#pragma unroll
    for (int c = 0; c < 4; ++c) {
      const short* vp = VTb + (size_t)(c * 16 + fr) * LEN + kv0 + fg * 8;
      vb[c][0] = *reinterpret_cast<const s16x8*>(vp);
      vb[c][1] = *reinterpret_cast<const s16x8*>(vp + 32);
    }
    s16x8 (*kc)[2] = (it & 1) ? kB : kA;
    s16x8 (*kn)[2] = (it & 1) ? kA : kB;
    // S^T tiles: D[kv][q], lane: q = fr, kv = s*16 + fg*4 + r
    fx4 sacc[4];
#pragma unroll
    for (int s = 0; s < 4; ++s) {
      fx4 z = fx4{0.f, 0.f, 0.f, 0.f};
      z = mfma16(kc[s][0], qa0, z);
      sacc[s] = mfma16(kc[s][1], qa1, z);
    }
    // prefetch next K tile under softmax+PV
    if (it + 1 < LEN / 64) {
#pragma unroll
      for (int s = 0; s < 4; ++s) {
        const short* kp = Kb + (size_t)(kv0 + 64 + s * 16 + fr) * HD + fg * 8;
        kn[s][0] = *reinterpret_cast<const s16x8*>(kp);
        kn[s][1] = *reinterpret_cast<const s16x8*>(kp + 32);
      }
    }
    // per-lane online softmax for q-row fr
    float xs[4][4];
    float xm = -1e30f;
#pragma unroll
    for (int s = 0; s < 4; ++s)
#pragma unroll
      for (int r = 0; r < 4; ++r) {
        xs[s][r] = sacc[s][r] * SC;
        xm = fmaxf(xm, xs[s][r]);
      }
    xm = fmaxf(xm, __shfl_xor(xm, 16, 64));
    xm = fmaxf(xm, __shfl_xor(xm, 32, 64));
    const float mn = fmaxf(mrun, xm);
    const float corr = __builtin_amdgcn_exp2f(mrun - mn);
    mrun = mn;
    float ps = 0.f;
    s16x4 pw[4];
#pragma unroll
    for (int s = 0; s < 4; ++s)
#pragma unroll
      for (int r = 0; r < 4; ++r) {
        float p = __builtin_amdgcn_exp2f(xs[s][r] - mn);
        ps += p;
        pw[s][r] = f2bf(p);
      }
    ps += __shfl_xor(ps, 16, 64);
    ps += __shfl_xor(ps, 32, 64);
    lsum = lsum * corr + ps;
    // P[q=fr][kv] -> LDS (4 consecutive bf16 per s)
#pragma unroll
    for (int s = 0; s < 4; ++s)
      *reinterpret_cast<s16x4*>(&Plds[wv][fr][s * 16 + fg * 4]) = pw[s];
    __builtin_amdgcn_wave_barrier();
    s16x8 pa0 = *reinterpret_cast<const s16x8*>(&Plds[wv][fr][fg * 8]);
    s16x8 pa1 = *reinterpret_cast<const s16x8*>(&Plds[wv][fr][32 + fg * 8]);
    // H^T += V^T P^T ; rescale is lane-local
#pragma unroll
    for (int c = 0; c < 4; ++c) {
      fx4 h = hacc[c];
#pragma unroll
      for (int r = 0; r < 4; ++r) h[r] *= corr;
      h = mfma16(vb[c][0], pa0, h);
      hacc[c] = mfma16(vb[c][1], pa1, h);
    }
  }
  const float inv = 1.0f / lsum;
  float* Ob = Out + ((size_t)b * LEN + qrow + fr) * HD;
#pragma unroll
  for (int c = 0; c < 4; ++c) {
    fx4 o;
#pragma unroll
    for (int r = 0; r < 4; ++r) o[r] = hacc[c][r] * inv;
    *reinterpret_cast<fx4*>(Ob + c * 16 + fg * 4) = o;
  }
}

extern "C" void kernel_launch(void* const* d_in, const int* in_sizes, int n_in,
                              void* d_out, int out_size, void* d_ws, size_t ws_size,
                              hipStream_t stream) {
  const float* dec = (const float*)d_in[0];
  const float* enc = (const float*)d_in[1];
  const float* Wq  = (const float*)d_in[2];
  const float* bq  = (const float*)d_in[3];
  const float* Wk  = (const float*)d_in[4];
  const float* bk  = (const float*)d_in[5];
  const float* Wv  = (const float*)d_in[6];
  const float* bv  = (const float*)d_in[7];
  float* out = (float*)d_out;

  short* wbuf = (short*)d_ws;                        // [3][49152] bf16 weights
  short* qws  = wbuf + 3 * (size_t)WELEM;            // [16384,64]
  short* kws  = qws + (size_t)M_TOT * HD;            // [16384,64]
  short* vtws = kws + (size_t)M_TOT * HD;            // [16,64,1024]

  convert_w_kernel<<<(3 * WELEM / 8) / 256, 256, 0, stream>>>(Wq, Wk, Wv, wbuf);
  proj_q_kernel<<<M_TOT / 64, 256, 0, stream>>>(dec, wbuf, bq, qws);
  proj_kv_kernel<<<M_TOT / 64, 256, 0, stream>>>(enc, wbuf + WELEM, bk,
                                                 wbuf + 2 * (size_t)WELEM, bv,
                                                 kws, vtws);
  attn_kernel<<<NB * (LEN / 64), 256, 0, stream>>>(qws, kws, vtws, out);
}

// Round 3
// 67.715 us; speedup vs baseline: 1.5006x; 1.5006x over previous
//
#include <hip/hip_runtime.h>

typedef __attribute__((ext_vector_type(8))) short s16x8;
typedef __attribute__((ext_vector_type(4))) short s16x4;
typedef __attribute__((ext_vector_type(4))) float fx4;

#define DEVINL __device__ __forceinline__

constexpr int EMBED = 768;
constexpr int HD    = 64;
constexpr int NB    = 16;
constexpr int LEN   = 1024;
constexpr int M_TOT = NB * LEN;  // 16384
constexpr int KVH   = LEN / 2;   // 512 per attention half

// fp32 -> bf16 (RNE). Inputs are well-behaved (no NaN/Inf).
DEVINL short f2bf(float f) {
  union { float f; unsigned u; } c; c.f = f;
  unsigned r = c.u + 0x7FFFu + ((c.u >> 16) & 1u);
  return (short)(r >> 16);
}

DEVINL fx4 mfma16(s16x8 a, s16x8 b, fx4 c) {
  return __builtin_amdgcn_mfma_f32_16x16x32_bf16(a, b, c, 0, 0, 0);
}

// ---------------------------------------------------------------------------
// proj_q: Y[m][d] = bf16( X[m][:] @ W[d][:] + b[d] ), X fp32 [16384,768],
// W fp32 [64,768]. Block = 1024 threads = 16 waves = 4 K-groups x 4 waves.
// Group g reduces K range [g*192,(g+1)*192); partials summed through LDS.
// Coalesced LDS staging (proven r1) + register prefetch of the next K-step.
// Grid 256 -> 1 block/CU -> 4 waves/SIMD.
// ---------------------------------------------------------------------------
__global__ __launch_bounds__(1024, 4) void proj_q_kernel(
    const float* __restrict__ X, const float* __restrict__ W,
    const float* __restrict__ bias, short* __restrict__ Y)
{
  __shared__ short Xs[4][64][40];
  __shared__ short Ws[4][64][40];
  __shared__ float Red[64][68];
  const int t = threadIdx.x, wv = t >> 6, lane = t & 63;
  const int g = wv >> 2, wl = wv & 3, u = t & 255;
  const int fr = lane & 15, fg = lane >> 4;
  const int m0 = blockIdx.x * 64;
  const int srow = u >> 2, scol = (u & 3) * 8;

  const float* xrow = X + (size_t)(m0 + srow) * EMBED + g * 192 + scol;
  const float* wrow = W + (size_t)srow * EMBED + g * 192 + scol;

  fx4 acc[4];
#pragma unroll
  for (int c = 0; c < 4; ++c) acc[c] = fx4{0.f, 0.f, 0.f, 0.f};

  fx4 px0 = *reinterpret_cast<const fx4*>(xrow);
  fx4 px1 = *reinterpret_cast<const fx4*>(xrow + 4);
  fx4 pw0 = *reinterpret_cast<const fx4*>(wrow);
  fx4 pw1 = *reinterpret_cast<const fx4*>(wrow + 4);

#pragma unroll
  for (int s = 0; s < 6; ++s) {
    s16x8 xb, wb;
#pragma unroll
    for (int j = 0; j < 4; ++j) {
      xb[j] = f2bf(px0[j]); xb[j + 4] = f2bf(px1[j]);
      wb[j] = f2bf(pw0[j]); wb[j + 4] = f2bf(pw1[j]);
    }
    __syncthreads();  // previous step's fragment reads complete
    *reinterpret_cast<s16x8*>(&Xs[g][srow][scol]) = xb;
    *reinterpret_cast<s16x8*>(&Ws[g][srow][scol]) = wb;
    if (s < 5) {  // prefetch next step; latency hides under MFMA + barriers
      px0 = *reinterpret_cast<const fx4*>(xrow + (s + 1) * 32);
      px1 = *reinterpret_cast<const fx4*>(xrow + (s + 1) * 32 + 4);
      pw0 = *reinterpret_cast<const fx4*>(wrow + (s + 1) * 32);
      pw1 = *reinterpret_cast<const fx4*>(wrow + (s + 1) * 32 + 4);
    }
    __syncthreads();
    s16x8 xa = *reinterpret_cast<const s16x8*>(&Xs[g][wl * 16 + fr][fg * 8]);
#pragma unroll
    for (int c = 0; c < 4; ++c) {
      s16x8 wf = *reinterpret_cast<const s16x8*>(&Ws[g][c * 16 + fr][fg * 8]);
      acc[c] = mfma16(wf, xa, acc[c]);  // D[d][m]: d=c*16+fg*4+r, m=wl*16+fr
    }
  }
  // cross-group reduce through LDS (sequential adds, 4 barriers)
  for (int gg = 0; gg < 4; ++gg) {
    if (g == gg) {
#pragma unroll
      for (int c = 0; c < 4; ++c) {
        float* p = &Red[wl * 16 + fr][c * 16 + fg * 4];
        if (gg == 0) {
          *reinterpret_cast<fx4*>(p) = acc[c];
        } else {
          fx4 v = *reinterpret_cast<fx4*>(p);
#pragma unroll
          for (int r = 0; r < 4; ++r) v[r] += acc[c][r];
          *reinterpret_cast<fx4*>(p) = v;
        }
      }
    }
    __syncthreads();
  }
  // epilogue: 1024 threads, 4 elems each
  const int row = t >> 4, d0 = (t & 15) * 4;
  fx4 v = *reinterpret_cast<const fx4*>(&Red[row][d0]);
  fx4 bv = *reinterpret_cast<const fx4*>(bias + d0);
  s16x4 o;
#pragma unroll
  for (int r = 0; r < 4; ++r) o[r] = f2bf(v[r] + bv[r]);
  *reinterpret_cast<s16x4*>(Y + (size_t)(m0 + row) * HD + d0) = o;
}

// ---------------------------------------------------------------------------
// proj_kv: enc -> K [b,kv,64] bf16 and V^T [b,64,kv] bf16. Same structure.
// ---------------------------------------------------------------------------
__global__ __launch_bounds__(1024, 4) void proj_kv_kernel(
    const float* __restrict__ X,
    const float* __restrict__ Wk, const float* __restrict__ bk,
    const float* __restrict__ Wv, const float* __restrict__ bv,
    short* __restrict__ Kout, short* __restrict__ VT)
{
  __shared__ short Xs[4][64][40];
  __shared__ short Wks[4][64][40];
  __shared__ short Wvs[4][64][40];
  __shared__ float Kred[64][68];
  __shared__ float Vred[64][68];
  const int t = threadIdx.x, wv = t >> 6, lane = t & 63;
  const int g = wv >> 2, wl = wv & 3, u = t & 255;
  const int fr = lane & 15, fg = lane >> 4;
  const int m0 = blockIdx.x * 64;
  const int srow = u >> 2, scol = (u & 3) * 8;

  const float* xrow  = X  + (size_t)(m0 + srow) * EMBED + g * 192 + scol;
  const float* wkrow = Wk + (size_t)srow * EMBED + g * 192 + scol;
  const float* wvrow = Wv + (size_t)srow * EMBED + g * 192 + scol;

  fx4 kacc[4], vacc[4];
#pragma unroll
  for (int c = 0; c < 4; ++c) {
    kacc[c] = fx4{0.f, 0.f, 0.f, 0.f};
    vacc[c] = fx4{0.f, 0.f, 0.f, 0.f};
  }

  fx4 px0 = *reinterpret_cast<const fx4*>(xrow);
  fx4 px1 = *reinterpret_cast<const fx4*>(xrow + 4);
  fx4 pk0 = *reinterpret_cast<const fx4*>(wkrow);
  fx4 pk1 = *reinterpret_cast<const fx4*>(wkrow + 4);
  fx4 pv0 = *reinterpret_cast<const fx4*>(wvrow);
  fx4 pv1 = *reinterpret_cast<const fx4*>(wvrow + 4);

#pragma unroll
  for (int s = 0; s < 6; ++s) {
    s16x8 xb, kb, vb;
#pragma unroll
    for (int j = 0; j < 4; ++j) {
      xb[j] = f2bf(px0[j]); xb[j + 4] = f2bf(px1[j]);
      kb[j] = f2bf(pk0[j]); kb[j + 4] = f2bf(pk1[j]);
      vb[j] = f2bf(pv0[j]); vb[j + 4] = f2bf(pv1[j]);
    }
    __syncthreads();
    *reinterpret_cast<s16x8*>(&Xs[g][srow][scol])  = xb;
    *reinterpret_cast<s16x8*>(&Wks[g][srow][scol]) = kb;
    *reinterpret_cast<s16x8*>(&Wvs[g][srow][scol]) = vb;
    if (s < 5) {
      px0 = *reinterpret_cast<const fx4*>(xrow + (s + 1) * 32);
      px1 = *reinterpret_cast<const fx4*>(xrow + (s + 1) * 32 + 4);
      pk0 = *reinterpret_cast<const fx4*>(wkrow + (s + 1) * 32);
      pk1 = *reinterpret_cast<const fx4*>(wkrow + (s + 1) * 32 + 4);
      pv0 = *reinterpret_cast<const fx4*>(wvrow + (s + 1) * 32);
      pv1 = *reinterpret_cast<const fx4*>(wvrow + (s + 1) * 32 + 4);
    }
    __syncthreads();
    s16x8 xa = *reinterpret_cast<const s16x8*>(&Xs[g][wl * 16 + fr][fg * 8]);
#pragma unroll
    for (int c = 0; c < 4; ++c) {
      s16x8 wkf = *reinterpret_cast<const s16x8*>(&Wks[g][c * 16 + fr][fg * 8]);
      s16x8 wvf = *reinterpret_cast<const s16x8*>(&Wvs[g][c * 16 + fr][fg * 8]);
      kacc[c] = mfma16(wkf, xa, kacc[c]);
      vacc[c] = mfma16(wvf, xa, vacc[c]);
    }
  }
  for (int gg = 0; gg < 4; ++gg) {
    if (g == gg) {
#pragma unroll
      for (int c = 0; c < 4; ++c) {
        float* pk = &Kred[wl * 16 + fr][c * 16 + fg * 4];
        float* pv = &Vred[wl * 16 + fr][c * 16 + fg * 4];
        if (gg == 0) {
          *reinterpret_cast<fx4*>(pk) = kacc[c];
          *reinterpret_cast<fx4*>(pv) = vacc[c];
        } else {
          fx4 a = *reinterpret_cast<fx4*>(pk);
          fx4 b = *reinterpret_cast<fx4*>(pv);
#pragma unroll
          for (int r = 0; r < 4; ++r) { a[r] += kacc[c][r]; b[r] += vacc[c][r]; }
          *reinterpret_cast<fx4*>(pk) = a;
          *reinterpret_cast<fx4*>(pv) = b;
        }
      }
    }
    __syncthreads();
  }
  // K epilogue: row-major bf16
  {
    const int row = t >> 4, d0 = (t & 15) * 4;
    fx4 v = *reinterpret_cast<const fx4*>(&Kred[row][d0]);
    fx4 bv4 = *reinterpret_cast<const fx4*>(bk + d0);
    s16x4 o;
#pragma unroll
    for (int r = 0; r < 4; ++r) o[r] = f2bf(v[r] + bv4[r]);
    *reinterpret_cast<s16x4*>(Kout + (size_t)(m0 + row) * HD + d0) = o;
  }
  // VT epilogue: transposed bf16 [b][d][kv]
  {
    const int d = t >> 4, seg = t & 15;
    const int bidx = m0 >> 10;             // 64 | 1024: no batch straddle
    const int kvpos = (m0 & 1023) + seg * 4;
    const float bvd = bv[d];
    s16x4 o;
#pragma unroll
    for (int j = 0; j < 4; ++j) o[j] = f2bf(Vred[seg * 4 + j][d] + bvd);
    *reinterpret_cast<s16x4*>(VT + ((size_t)(bidx * HD + d)) * LEN + kvpos) = o;
  }
}

// ---------------------------------------------------------------------------
// Flash attention, swapped operands, KV-split x2. blockIdx.y = half, each
// half covers 512 kv and writes unnormalized Hpart + (m,l) stats.
// 4 waves/block, 16 q rows/wave, KVBLK=64; lane-local softmax (2 shfl/iter);
// K register double-buffer prefetch; V issued before QK^T.
// ---------------------------------------------------------------------------
__global__ __launch_bounds__(256, 2) void attn_kernel(
    const short* __restrict__ Q, const short* __restrict__ K,
    const short* __restrict__ VT, float* __restrict__ Hpart,
    float2* __restrict__ stats)
{
  __shared__ short Plds[4][16][72];
  const int t = threadIdx.x, lane = t & 63, wv = t >> 6;
  const int fr = lane & 15, fg = lane >> 4;
  const int b  = blockIdx.x >> 4;
  const int qrow = (blockIdx.x & 15) * 64 + wv * 16;
  const int half = blockIdx.y;
  const int kvb  = half * KVH;

  const short* Qb  = Q  + (size_t)b * LEN * HD;
  const short* Kb  = K  + ((size_t)b * LEN + kvb) * HD;
  const short* VTb = VT + (size_t)b * HD * LEN + kvb;

  s16x8 qa0 = *reinterpret_cast<const s16x8*>(Qb + (size_t)(qrow + fr) * HD + fg * 8);
  s16x8 qa1 = *reinterpret_cast<const s16x8*>(Qb + (size_t)(qrow + fr) * HD + 32 + fg * 8);

  fx4 hacc[4];
#pragma unroll
  for (int c = 0; c < 4; ++c) hacc[c] = fx4{0.f, 0.f, 0.f, 0.f};
  float mrun = -1e30f, lsum = 0.f;
  const float SC = 0.125f * 1.44269504088896340736f;  // 1/sqrt(64) * log2(e)

  s16x8 kA[4][2], kB[4][2];
#pragma unroll
  for (int s = 0; s < 4; ++s) {
    const short* kp = Kb + (size_t)(s * 16 + fr) * HD + fg * 8;
    kA[s][0] = *reinterpret_cast<const s16x8*>(kp);
    kA[s][1] = *reinterpret_cast<const s16x8*>(kp + 32);
  }

#pragma unroll
  for (int it = 0; it < KVH / 64; ++it) {
    const int kv0 = it * 64;
    s16x8 vb[4][2];
#pragma unroll
    for (int c = 0; c < 4; ++c) {
      const short* vp = VTb + (size_t)(c * 16 + fr) * LEN + kv0 + fg * 8;
      vb[c][0] = *reinterpret_cast<const s16x8*>(vp);
      vb[c][1] = *reinterpret_cast<const s16x8*>(vp + 32);
    }
    s16x8 (*kc)[2] = (it & 1) ? kB : kA;
    s16x8 (*kn)[2] = (it & 1) ? kA : kB;
    fx4 sacc[4];
#pragma unroll
    for (int s = 0; s < 4; ++s) {
      fx4 z = fx4{0.f, 0.f, 0.f, 0.f};
      z = mfma16(kc[s][0], qa0, z);
      sacc[s] = mfma16(kc[s][1], qa1, z);
    }
    if (it + 1 < KVH / 64) {
#pragma unroll
      for (int s = 0; s < 4; ++s) {
        const short* kp = Kb + (size_t)(kv0 + 64 + s * 16 + fr) * HD + fg * 8;
        kn[s][0] = *reinterpret_cast<const s16x8*>(kp);
        kn[s][1] = *reinterpret_cast<const s16x8*>(kp + 32);
      }
    }
    float xs[4][4];
    float xm = -1e30f;
#pragma unroll
    for (int s = 0; s < 4; ++s)
#pragma unroll
      for (int r = 0; r < 4; ++r) {
        xs[s][r] = sacc[s][r] * SC;
        xm = fmaxf(xm, xs[s][r]);
      }
    xm = fmaxf(xm, __shfl_xor(xm, 16, 64));
    xm = fmaxf(xm, __shfl_xor(xm, 32, 64));
    const float mn = fmaxf(mrun, xm);
    const float corr = __builtin_amdgcn_exp2f(mrun - mn);
    mrun = mn;
    float ps = 0.f;
    s16x4 pw[4];
#pragma unroll
    for (int s = 0; s < 4; ++s)
#pragma unroll
      for (int r = 0; r < 4; ++r) {
        float p = __builtin_amdgcn_exp2f(xs[s][r] - mn);
        ps += p;
        pw[s][r] = f2bf(p);
      }
    ps += __shfl_xor(ps, 16, 64);
    ps += __shfl_xor(ps, 32, 64);
    lsum = lsum * corr + ps;
#pragma unroll
    for (int s = 0; s < 4; ++s)
      *reinterpret_cast<s16x4*>(&Plds[wv][fr][s * 16 + fg * 4]) = pw[s];
    __builtin_amdgcn_wave_barrier();
    s16x8 pa0 = *reinterpret_cast<const s16x8*>(&Plds[wv][fr][fg * 8]);
    s16x8 pa1 = *reinterpret_cast<const s16x8*>(&Plds[wv][fr][32 + fg * 8]);
#pragma unroll
    for (int c = 0; c < 4; ++c) {
      fx4 h = hacc[c];
#pragma unroll
      for (int r = 0; r < 4; ++r) h[r] *= corr;
      h = mfma16(vb[c][0], pa0, h);
      hacc[c] = mfma16(vb[c][1], pa1, h);
    }
  }
  // unnormalized partial + stats
  float* Hp = Hpart + ((size_t)(half * NB + b) * LEN + qrow + fr) * HD;
#pragma unroll
  for (int c = 0; c < 4; ++c)
    *reinterpret_cast<fx4*>(Hp + c * 16 + fg * 4) = hacc[c];
  if (fg == 0)
    stats[(size_t)half * M_TOT + (size_t)b * LEN + qrow + fr] = make_float2(mrun, lsum);
}

// ---------------------------------------------------------------------------
// Combine the two KV halves: out = (H0*w0 + H1*w1) / (l0*w0 + l1*w1).
// ---------------------------------------------------------------------------
__global__ __launch_bounds__(256) void combine_kernel(
    const float* __restrict__ Hpart, const float2* __restrict__ stats,
    float* __restrict__ Out)
{
  const int t = threadIdx.x;
  const int row = blockIdx.x * 16 + (t >> 4);
  const int d0 = (t & 15) * 4;
  const float2 s0 = stats[row];
  const float2 s1 = stats[M_TOT + row];
  const float m  = fmaxf(s0.x, s1.x);
  const float w0 = __builtin_amdgcn_exp2f(s0.x - m);
  const float w1 = __builtin_amdgcn_exp2f(s1.x - m);
  const float inv = 1.0f / (s0.y * w0 + s1.y * w1);
  fx4 h0 = *reinterpret_cast<const fx4*>(Hpart + (size_t)row * HD + d0);
  fx4 h1 = *reinterpret_cast<const fx4*>(Hpart + ((size_t)M_TOT + row) * HD + d0);
  fx4 o;
#pragma unroll
  for (int r = 0; r < 4; ++r) o[r] = (h0[r] * w0 + h1[r] * w1) * inv;
  *reinterpret_cast<fx4*>(Out + (size_t)row * HD + d0) = o;
}

extern "C" void kernel_launch(void* const* d_in, const int* in_sizes, int n_in,
                              void* d_out, int out_size, void* d_ws, size_t ws_size,
                              hipStream_t stream) {
  const float* dec = (const float*)d_in[0];
  const float* enc = (const float*)d_in[1];
  const float* Wq  = (const float*)d_in[2];
  const float* bq  = (const float*)d_in[3];
  const float* Wk  = (const float*)d_in[4];
  const float* bk  = (const float*)d_in[5];
  const float* Wv  = (const float*)d_in[6];
  const float* bv  = (const float*)d_in[7];
  float* out = (float*)d_out;

  short* qws  = (short*)d_ws;                        // [16384,64] bf16
  short* kws  = qws + (size_t)M_TOT * HD;            // [16384,64] bf16
  short* vtws = kws + (size_t)M_TOT * HD;            // [16,64,1024] bf16
  float* hpart = (float*)(vtws + (size_t)NB * HD * LEN);  // [2,16384,64] fp32
  float2* stats = (float2*)(hpart + (size_t)2 * M_TOT * HD);  // [2,16384]

  proj_q_kernel<<<M_TOT / 64, 1024, 0, stream>>>(dec, Wq, bq, qws);
  proj_kv_kernel<<<M_TOT / 64, 1024, 0, stream>>>(enc, Wk, bk, Wv, bv, kws, vtws);
  attn_kernel<<<dim3(NB * (LEN / 64), 2), 256, 0, stream>>>(qws, kws, vtws, hpart, stats);
  combine_kernel<<<M_TOT / 16, 256, 0, stream>>>(hpart, stats, out);
}